// Round 6
// baseline (701.322 us; speedup 1.0000x reference)
//
#include <hip/hip_runtime.h>
#include <hip/hip_bf16.h>

// Fused masked SDPA: B=64, LQ=LK=1024, D=64, temperature=8.
// R9: FULL-LINE memory transactions everywhere. All prior rounds issued the
// two 268MB streams (MSK read, OUT_P write) as scattered 64B half-lines
// (4B/lane, 16-lane runs, 4KB apart); request-slot BW model caps that at
// ~1.7 TB/s device-wide -- the exact plateau measured in R0-R8, insensitive
// to every pipelining scheme tried.
//  - MSK: wave reads 64 consecutive ints (2 full lines/instr), __ballot ->
//    u64, AND with pre-balloted key-mask u64, store 16x16-u64 bitmap in LDS
//    (bank-padded). Consumed as register bits at the exp stage (R7-proven:
//    unmasked max is a valid softmax shift).
//  - OUT_P: pass 2 writes p=e*Cr back into sreg; epilogue stages 4-row
//    chunks into LDS and drains f32x4/thread = contiguous 4KB rows.
//  - K: back to R3's coalesced private-slice staging (full 256B row loads;
//    R4's "direct frags" were half-line requests). V: R3 (already good).
//  - LDS 27.3KB (K/V/O/Pstage share region A) -> 5 blocks/CU = 20 waves
//    (was ~11): 2x latency hiding on top of granularity fix.
//  - Softmax: registered S, one exp pass; hw cvt; Q prescaled 1/8.

#define NB   64
#define SLQ  1024
#define SLK  1024
#define DH   64
#define TQ   16
#define TK   64
#define NKT  16
#define KSTR 80    // K slice row stride (u16)
#define VSTR 76    // V slice row stride (u16)
#define PSTR 40    // P bf16 slice row stride (u16)
#define OSTR 68    // O partial row stride (f32)
#define PGSTR 1028 // P f32 stage row stride (f32): +4 pad

typedef __attribute__((ext_vector_type(4))) float          f32x4;
typedef __attribute__((ext_vector_type(8))) __bf16         bf16x8;
typedef __attribute__((ext_vector_type(8))) unsigned short u16x8;
typedef __attribute__((ext_vector_type(4))) unsigned short u16x4;

static __device__ __forceinline__ unsigned short f2bf(float f) {
  return __builtin_bit_cast(unsigned short, (__bf16)f);   // hw cvt, RTNE
}
static __device__ __forceinline__ bf16x8 cvt8(f32x4 a, f32x4 b) {
  bf16x8 r;
#pragma unroll
  for (int i = 0; i < 4; ++i) { r[i] = (__bf16)a[i]; r[i + 4] = (__bf16)b[i]; }
  return r;
}
static __device__ __forceinline__ u16x4 cvt4(f32x4 v) {
  u16x4 h;
#pragma unroll
  for (int i = 0; i < 4; ++i) h[i] = f2bf(v[i]);
  return h;
}

__global__ __launch_bounds__(256, 4) void sdpa_fused(
    const float* __restrict__ Q, const float* __restrict__ K,
    const float* __restrict__ V, const int* __restrict__ QM,
    const int* __restrict__ KM, const int* __restrict__ MSK,
    float* __restrict__ OUT_AV, float* __restrict__ OUT_P) {
  // XCD swizzle: co-schedule same-batch blocks on one XCD for K/V L2 reuse
  const int g    = blockIdx.x;
  const int slot = g >> 3;
  const int b    = ((slot >> 6) << 3) | (g & 7);
  const int q0   = (slot & 63) * TQ;

  const int tid  = threadIdx.x;
  const int wave = tid >> 6;
  const int lane = tid & 63;
  const int col  = lane & 15;
  const int quad = lane >> 4;
  const int lrow = quad;             // staging row subgroup
  const int lc4  = col * 4;          // staging column (x4 elements)

  // LDS map:
  //  A: [0,19456)      Kw slices (pass1) / Vw slices+Ow partials (pass2)
  //                    / P f32 stage (epilogue)  -- disjoint in time
  //  B: [19456,24576)  P bf16 slices (4 waves x 1280B)
  //  C: [24576,25216)  softmax stats
  //  D: [25216,27328)  mask bitmap u32[16][33] (+1 word row pad)
  __shared__ __align__(16) unsigned char RAW[27328];
  unsigned short* Kw = (unsigned short*)RAW + wave * (16 * KSTR);
  unsigned short* Vw = (unsigned short*)(RAW + wave * (32 * VSTR * 2));
  float*          Ow = (float*)(RAW + wave * (32 * VSTR * 2));
  float*          Pst = (float*)RAW;
  unsigned short* Pw = (unsigned short*)(RAW + 19456) + wave * (16 * PSTR);
  float* partM = (float*)(RAW + 24576);
  float* partL = partM + 64;
  float* rowM  = partL + 64;
  float* rowS  = rowM + 16;
  unsigned* bm = (unsigned*)(RAW + 25216);

  const size_t mbase = ((size_t)b * SLQ + q0) * SLK;
  const f32x4* kb4 = (const f32x4*)(K + (size_t)b * SLK * DH);
  const f32x4* vb4 = (const f32x4*)(V + (size_t)b * SLK * DH);

  // ---- Q A-frags from global, pre-scaled by 1/8 (exact exponent shift) ----
  const float* qp = Q + ((size_t)b * SLQ + q0 + col) * DH + quad * 8;
  bf16x8 aq0, aq1;
  {
    f32x4 a = *(const f32x4*)qp        * 0.125f;
    f32x4 c = *(const f32x4*)(qp + 4)  * 0.125f;
    f32x4 d = *(const f32x4*)(qp + 32) * 0.125f;
    f32x4 e = *(const f32x4*)(qp + 36) * 0.125f;
    aq0 = cvt8(a, c);
    aq1 = cvt8(d, e);
  }

  // ---- K tile 0 prefetch (coalesced full rows), in flight over mask phase -
  f32x4 kreg[4];
#pragma unroll
  for (int j = 0; j < 4; ++j)
    kreg[j] = kb4[(size_t)(wave * 16 + j * 4 + lrow) * 16 + col];

  // ====== mask phase: ballot to bitmap (all requests = full 128B lines) ====
  // key-mask u64 per 64-key chunk (each wave redundantly; KM is 4KB, L2-hot)
  const int* kmB = KM + b * SLK;
  unsigned long long kmb[16];
#pragma unroll
  for (int c = 0; c < 16; ++c)
    kmb[c] = __ballot(kmB[c * 64 + lane] != 0);

  // wave w ballots rows w*4 .. w*4+3; 64 consecutive ints per load (256B)
  const int* mrow = MSK + mbase;
#pragma unroll
  for (int rr = 0; rr < 4; ++rr) {
    const int row = wave * 4 + rr;
    int mv[16];
#pragma unroll
    for (int c = 0; c < 16; ++c)
      mv[c] = mrow[(size_t)row * SLK + c * 64 + lane];
#pragma unroll
    for (int c = 0; c < 16; ++c) {
      unsigned long long mb_ = __ballot(mv[c] != 0) & kmb[c];
      if (lane < 2) bm[row * 33 + c * 2 + lane] = (unsigned)(mb_ >> (lane * 32));
    }
  }
  __syncthreads();   // bitmap visible to all waves

  // =================== Pass 1 (barrier-free): S = (Q/8)K^T =================
  float sreg[NKT][4];
#pragma unroll
  for (int kt = 0; kt < NKT; ++kt) {
    // stage this wave's 16 K rows into its private slice
#pragma unroll
    for (int j = 0; j < 4; ++j)
      *(u16x4*)&Kw[(j * 4 + lrow) * KSTR + lc4] = cvt4(kreg[j]);

    // prefetch tile kt+1 (coalesced full rows)
    if (kt < NKT - 1) {
      const int brow = (kt + 1) * TK + wave * 16;
#pragma unroll
      for (int j = 0; j < 4; ++j)
        kreg[j] = kb4[(size_t)(brow + j * 4 + lrow) * 16 + col];
    }

    // B-frag: K[key = wave*16+col][k = quad*8+j (+32)]
    bf16x8 bk0 = __builtin_bit_cast(bf16x8, *(const u16x8*)&Kw[col * KSTR + quad * 8]);
    bf16x8 bk1 = __builtin_bit_cast(bf16x8, *(const u16x8*)&Kw[col * KSTR + quad * 8 + 32]);
    f32x4 acc = {0.f, 0.f, 0.f, 0.f};
    acc = __builtin_amdgcn_mfma_f32_16x16x32_bf16(aq0, bk0, acc, 0, 0, 0);
    acc = __builtin_amdgcn_mfma_f32_16x16x32_bf16(aq1, bk1, acc, 0, 0, 0);
#pragma unroll
    for (int r = 0; r < 4; ++r) sreg[kt][r] = acc[r];   // raw, unmasked
  }

  // prefetch V step 0 (2 tiles x this wave's 16 rows) during stats phase
  f32x4 vreg[8];
#pragma unroll
  for (int j = 0; j < 8; ++j)
    vreg[j] = vb4[(size_t)((j >> 2) * TK + wave * 16 + (j & 3) * 4 + lrow) * 16 + col];

  // ---- gather this lane's 64 mask bits from the bitmap -------------------
  const int sh = (wave & 1) * 16 + col;
  const int wh = wave >> 1;
  unsigned mbits0 = 0u, mbits1 = 0u;   // bit (kt&7)*4+r of mbits[kt>>3]
#pragma unroll
  for (int kt = 0; kt < NKT; ++kt)
#pragma unroll
    for (int r = 0; r < 4; ++r) {
      unsigned bit = (bm[(quad * 4 + r) * 33 + kt * 2 + wh] >> sh) & 1u;
      if (kt < 8) mbits0 |= bit << ((kt & 7) * 4 + r);
      else        mbits1 |= bit << ((kt & 7) * 4 + r);
    }

  // ====== stats: unmasked max -> butterfly -> masked exp pass -> sum =======
  float Mw[4], Cr[4];
#pragma unroll
  for (int r = 0; r < 4; ++r) {
    float m = sreg[0][r];
#pragma unroll
    for (int kt = 1; kt < NKT; ++kt) m = fmaxf(m, sreg[kt][r]);
#pragma unroll
    for (int off = 1; off < 16; off <<= 1) m = fmaxf(m, __shfl_xor(m, off, 64));
    Mw[r] = m;
    float l = 0.f;
#pragma unroll
    for (int kt = 0; kt < NKT; ++kt) {
      float e = __expf(sreg[kt][r] - m);
      const unsigned mb = (kt < 8) ? mbits0 : mbits1;
      e = ((mb >> ((kt & 7) * 4 + r)) & 1u) ? e : 0.f;
      sreg[kt][r] = e;                 // reuse in pass 2: p = e * Cr
      l += e;
    }
#pragma unroll
    for (int off = 1; off < 16; off <<= 1) l += __shfl_xor(l, off, 64);
    if (col == 0) {
      partM[wave * 16 + quad * 4 + r] = m;
      partL[wave * 16 + quad * 4 + r] = l;
    }
  }
  __syncthreads();
  if (tid < TQ) {
    float M = -INFINITY, L = 0.f;
#pragma unroll
    for (int w = 0; w < 4; ++w) {
      float m_ = partM[w * 16 + tid], l_ = partL[w * 16 + tid];
      float mn = fmaxf(M, m_);
      L = L * __expf(M - mn) + l_ * __expf(m_ - mn);  // finite inputs
      M = mn;
    }
    rowM[tid] = M;
    rowS[tid] = (QM[b * SLQ + q0 + tid] && L > 0.f) ? (1.f / L) : 0.f;
  }
  __syncthreads();
#pragma unroll
  for (int r = 0; r < 4; ++r)
    Cr[r] = __expf(Mw[r] - rowM[quad * 4 + r]) * rowS[quad * 4 + r];

  // ====== Pass 2 (barrier-free): 8 steps of 2 tiles, V via private LDS =====
  f32x4 acco[4] = {{0.f,0.f,0.f,0.f},{0.f,0.f,0.f,0.f},
                   {0.f,0.f,0.f,0.f},{0.f,0.f,0.f,0.f}};
#pragma unroll
  for (int st = 0; st < 8; ++st) {
    const int kt0 = st * 2, kt1 = kt0 + 1;
    // stage V rows (32: tile kt0 then kt1) into private slice
#pragma unroll
    for (int j = 0; j < 8; ++j)
      *(u16x4*)&Vw[(j * 4 + lrow) * VSTR + lc4] = cvt4(vreg[j]);

    // p = e*Cr: write back into sreg (f32, for staged output) + bf16 slice
#pragma unroll
    for (int r = 0; r < 4; ++r) {
      float p0 = sreg[kt0][r] * Cr[r];
      float p1 = sreg[kt1][r] * Cr[r];
      sreg[kt0][r] = p0;
      sreg[kt1][r] = p1;
      Pw[(quad * 4 + r) * PSTR + col]      = f2bf(p0);
      Pw[(quad * 4 + r) * PSTR + 16 + col] = f2bf(p1);
    }

    // prefetch next step's V
    if (st < 7) {
#pragma unroll
      for (int j = 0; j < 8; ++j)
        vreg[j] = vb4[(size_t)((st * 2 + 2 + (j >> 2)) * TK + wave * 16 + (j & 3) * 4 + lrow) * 16
                      + col];
    }

    // A = P[q=col][kk=quad*8+j]; B = V[kk=quad*8+j][d=n0*16+col]
    bf16x8 ap = __builtin_bit_cast(bf16x8, *(const u16x8*)&Pw[col * PSTR + quad * 8]);
#pragma unroll
    for (int n0 = 0; n0 < 4; ++n0) {
      u16x8 rv;
#pragma unroll
      for (int j = 0; j < 8; ++j)
        rv[j] = Vw[(quad * 8 + j) * VSTR + n0 * 16 + col];
      acco[n0] = __builtin_amdgcn_mfma_f32_16x16x32_bf16(
          ap, __builtin_bit_cast(bf16x8, rv), acco[n0], 0, 0, 0);
    }
  }

  // ====== final O: per-wave partial -> LDS (aliases dead V) -> reduce ======
#pragma unroll
  for (int n0 = 0; n0 < 4; ++n0)
#pragma unroll
    for (int r = 0; r < 4; ++r)
      Ow[(quad * 4 + r) * OSTR + n0 * 16 + col] = acco[n0][r];
  __syncthreads();
  {
    const int qq = tid >> 4, dd = (tid & 15) * 4;
    f32x4 s = {0.f, 0.f, 0.f, 0.f};
#pragma unroll
    for (int w = 0; w < 4; ++w) {
      const float* Os = (const float*)(RAW + w * (32 * VSTR * 2));
      s += *(const f32x4*)&Os[qq * OSTR + dd];
    }
    *(f32x4*)&OUT_AV[((size_t)b * SLQ + q0 + qq) * DH + dd] = s;
  }
  __syncthreads();   // region A now free for P staging

  // ====== P f32 output: stage 4-row chunks, drain contiguous rows ==========
#pragma unroll
  for (int c = 0; c < 4; ++c) {
    if (quad == c) {
#pragma unroll
      for (int kt = 0; kt < NKT; ++kt)
#pragma unroll
        for (int r = 0; r < 4; ++r)
          Pst[r * PGSTR + kt * TK + wave * 16 + col] = sreg[kt][r];
    }
    __syncthreads();
    {
      float* dst = OUT_P + mbase + (size_t)(c * 4) * SLK;
#pragma unroll
      for (int i = 0; i < 4; ++i)
        *(f32x4*)&dst[(size_t)i * SLK + tid * 4] =
            *(const f32x4*)&Pst[i * PGSTR + tid * 4];
    }
    if (c < 3) __syncthreads();
  }
}

extern "C" void kernel_launch(void* const* d_in, const int* in_sizes, int n_in,
                              void* d_out, int out_size, void* d_ws, size_t ws_size,
                              hipStream_t stream) {
  const float* q  = (const float*)d_in[0];
  const float* k  = (const float*)d_in[1];
  const float* v  = (const float*)d_in[2];
  const int*   qm = (const int*)d_in[3];
  const int*   km = (const int*)d_in[4];
  const int*   mk = (const int*)d_in[5];
  float* out_av = (float*)d_out;                          // [B,LQ,D]
  float* out_p  = out_av + (size_t)NB * SLQ * DH;         // [B,LQ,LK]
  sdpa_fused<<<dim3(NB * (SLQ / TQ)), dim3(256), 0, stream>>>(q, k, v, qm, km, mk, out_av, out_p);
}

// Round 8
// 582.264 us; speedup vs baseline: 1.2045x; 1.2045x over previous
//
#include <hip/hip_runtime.h>
#include <hip/hip_bf16.h>

// Fused masked SDPA: B=64, LQ=LK=1024, D=64, temperature=8.
// R11 = R9's exact mask phase (HW-proven) + launch_bounds(256,3) (kills the
// R9 spill: bounds-4 squeezed 84->64 VGPR, +330MB scratch traffic) + a hard
// fence closing the one unfenced LDS aliasing window that explains R10's
// nondeterministic OUT_AV corruption:
//   pass 2 ends with u16 reads of Vw/Pw; the f32 Ow partial writes land in
//   the SAME bytes (Ow aliases Vw by design). TBAA treats float*/ushort*
//   LDS accesses as non-aliasing, so the scheduler may move the Ow stores
//   above the final Vw reads; whether it does depends on codegen context
//   (R10's mask-phase restructure flipped it). __syncthreads() here is both
//   a compiler memory barrier and a wave sync -- closes the class.
//  - kept (validated): full-line transactions everywhere (ballot mask ->
//    bitmap; staged f32 P epilogue; coalesced K/V private-slice staging),
//    mask bits consumed at exp stage (unmasked max = valid softmax shift),
//    one-exp softmax, hw v_cvt bf16, Q prescaled 1/8.

#define NB   64
#define SLQ  1024
#define SLK  1024
#define DH   64
#define TQ   16
#define TK   64
#define NKT  16
#define KSTR 80    // K slice row stride (u16)
#define VSTR 76    // V slice row stride (u16)
#define PSTR 40    // P bf16 slice row stride (u16)
#define OSTR 68    // O partial row stride (f32)
#define PGSTR 1028 // P f32 stage row stride (f32): +4 pad

typedef __attribute__((ext_vector_type(4))) float          f32x4;
typedef __attribute__((ext_vector_type(8))) __bf16         bf16x8;
typedef __attribute__((ext_vector_type(8))) unsigned short u16x8;
typedef __attribute__((ext_vector_type(4))) unsigned short u16x4;

static __device__ __forceinline__ unsigned short f2bf(float f) {
  return __builtin_bit_cast(unsigned short, (__bf16)f);   // hw cvt, RTNE
}
static __device__ __forceinline__ bf16x8 cvt8(f32x4 a, f32x4 b) {
  bf16x8 r;
#pragma unroll
  for (int i = 0; i < 4; ++i) { r[i] = (__bf16)a[i]; r[i + 4] = (__bf16)b[i]; }
  return r;
}
static __device__ __forceinline__ u16x4 cvt4(f32x4 v) {
  u16x4 h;
#pragma unroll
  for (int i = 0; i < 4; ++i) h[i] = f2bf(v[i]);
  return h;
}

__global__ __launch_bounds__(256, 3) void sdpa_fused(
    const float* __restrict__ Q, const float* __restrict__ K,
    const float* __restrict__ V, const int* __restrict__ QM,
    const int* __restrict__ KM, const int* __restrict__ MSK,
    float* __restrict__ OUT_AV, float* __restrict__ OUT_P) {
  // XCD swizzle: co-schedule same-batch blocks on one XCD for K/V L2 reuse
  const int g    = blockIdx.x;
  const int slot = g >> 3;
  const int b    = ((slot >> 6) << 3) | (g & 7);
  const int q0   = (slot & 63) * TQ;

  const int tid  = threadIdx.x;
  const int wave = tid >> 6;
  const int lane = tid & 63;
  const int col  = lane & 15;
  const int quad = lane >> 4;
  const int lrow = quad;             // staging row subgroup
  const int lc4  = col * 4;          // staging column (x4 elements)

  // LDS map:
  //  A: [0,19456)      Kw slices (pass1) / Vw slices+Ow partials (pass2)
  //                    / P f32 stage (epilogue)  -- disjoint in time
  //  B: [19456,24576)  P bf16 slices (4 waves x 1280B)
  //  C: [24576,25216)  softmax stats
  //  D: [25216,27328)  mask bitmap u32[16][33] (+1 word row pad)
  __shared__ __align__(16) unsigned char RAW[27328];
  unsigned short* Kw = (unsigned short*)RAW + wave * (16 * KSTR);
  unsigned short* Vw = (unsigned short*)(RAW + wave * (32 * VSTR * 2));
  float*          Ow = (float*)(RAW + wave * (32 * VSTR * 2));
  float*          Pst = (float*)RAW;
  unsigned short* Pw = (unsigned short*)(RAW + 19456) + wave * (16 * PSTR);
  float* partM = (float*)(RAW + 24576);
  float* partL = partM + 64;
  float* rowM  = partL + 64;
  float* rowS  = rowM + 16;
  unsigned* bm = (unsigned*)(RAW + 25216);

  const size_t mbase = ((size_t)b * SLQ + q0) * SLK;
  const f32x4* kb4 = (const f32x4*)(K + (size_t)b * SLK * DH);
  const f32x4* vb4 = (const f32x4*)(V + (size_t)b * SLK * DH);

  // ---- Q A-frags from global, pre-scaled by 1/8 (exact exponent shift) ----
  const float* qp = Q + ((size_t)b * SLQ + q0 + col) * DH + quad * 8;
  bf16x8 aq0, aq1;
  {
    f32x4 a = *(const f32x4*)qp        * 0.125f;
    f32x4 c = *(const f32x4*)(qp + 4)  * 0.125f;
    f32x4 d = *(const f32x4*)(qp + 32) * 0.125f;
    f32x4 e = *(const f32x4*)(qp + 36) * 0.125f;
    aq0 = cvt8(a, c);
    aq1 = cvt8(d, e);
  }

  // ---- K tile 0 prefetch (coalesced full rows), in flight over mask phase -
  f32x4 kreg[4];
#pragma unroll
  for (int j = 0; j < 4; ++j)
    kreg[j] = kb4[(size_t)(wave * 16 + j * 4 + lrow) * 16 + col];

  // ====== mask phase (R9 exact): ballot to bitmap, full-line loads =========
  // key-mask u64 per 64-key chunk (each wave redundantly; KM is 4KB, L2-hot)
  const int* kmB = KM + b * SLK;
  unsigned long long kmb[16];
#pragma unroll
  for (int c = 0; c < 16; ++c)
    kmb[c] = __ballot(kmB[c * 64 + lane] != 0);

  // wave w ballots rows w*4 .. w*4+3; 64 consecutive ints per load (256B)
  const int* mrow = MSK + mbase;
#pragma unroll
  for (int rr = 0; rr < 4; ++rr) {
    const int row = wave * 4 + rr;
    int mv[16];
#pragma unroll
    for (int c = 0; c < 16; ++c)
      mv[c] = mrow[(size_t)row * SLK + c * 64 + lane];
#pragma unroll
    for (int c = 0; c < 16; ++c) {
      unsigned long long mb_ = __ballot(mv[c] != 0) & kmb[c];
      if (lane < 2) bm[row * 33 + c * 2 + lane] = (unsigned)(mb_ >> (lane * 32));
    }
  }
  __syncthreads();   // bitmap visible to all waves

  // =================== Pass 1 (barrier-free): S = (Q/8)K^T =================
  float sreg[NKT][4];
#pragma unroll
  for (int kt = 0; kt < NKT; ++kt) {
    // stage this wave's 16 K rows into its private slice
#pragma unroll
    for (int j = 0; j < 4; ++j)
      *(u16x4*)&Kw[(j * 4 + lrow) * KSTR + lc4] = cvt4(kreg[j]);

    // prefetch tile kt+1 (coalesced full rows)
    if (kt < NKT - 1) {
      const int brow = (kt + 1) * TK + wave * 16;
#pragma unroll
      for (int j = 0; j < 4; ++j)
        kreg[j] = kb4[(size_t)(brow + j * 4 + lrow) * 16 + col];
    }

    // B-frag: K[key = wave*16+col][k = quad*8+j (+32)]
    bf16x8 bk0 = __builtin_bit_cast(bf16x8, *(const u16x8*)&Kw[col * KSTR + quad * 8]);
    bf16x8 bk1 = __builtin_bit_cast(bf16x8, *(const u16x8*)&Kw[col * KSTR + quad * 8 + 32]);
    f32x4 acc = {0.f, 0.f, 0.f, 0.f};
    acc = __builtin_amdgcn_mfma_f32_16x16x32_bf16(aq0, bk0, acc, 0, 0, 0);
    acc = __builtin_amdgcn_mfma_f32_16x16x32_bf16(aq1, bk1, acc, 0, 0, 0);
#pragma unroll
    for (int r = 0; r < 4; ++r) sreg[kt][r] = acc[r];   // raw, unmasked
  }

  // prefetch V step 0 (2 tiles x this wave's 16 rows) during stats phase
  f32x4 vreg[8];
#pragma unroll
  for (int j = 0; j < 8; ++j)
    vreg[j] = vb4[(size_t)((j >> 2) * TK + wave * 16 + (j & 3) * 4 + lrow) * 16 + col];

  // ---- gather this lane's 64 mask bits from the bitmap -------------------
  const int sh = (wave & 1) * 16 + col;
  const int wh = wave >> 1;
  unsigned mbits0 = 0u, mbits1 = 0u;   // bit (kt&7)*4+r of mbits[kt>>3]
#pragma unroll
  for (int kt = 0; kt < NKT; ++kt)
#pragma unroll
    for (int r = 0; r < 4; ++r) {
      unsigned bit = (bm[(quad * 4 + r) * 33 + kt * 2 + wh] >> sh) & 1u;
      if (kt < 8) mbits0 |= bit << ((kt & 7) * 4 + r);
      else        mbits1 |= bit << ((kt & 7) * 4 + r);
    }

  // ====== stats: unmasked max -> butterfly -> masked exp pass -> sum =======
  float Mw[4], Cr[4];
#pragma unroll
  for (int r = 0; r < 4; ++r) {
    float m = sreg[0][r];
#pragma unroll
    for (int kt = 1; kt < NKT; ++kt) m = fmaxf(m, sreg[kt][r]);
#pragma unroll
    for (int off = 1; off < 16; off <<= 1) m = fmaxf(m, __shfl_xor(m, off, 64));
    Mw[r] = m;
    float l = 0.f;
#pragma unroll
    for (int kt = 0; kt < NKT; ++kt) {
      float e = __expf(sreg[kt][r] - m);
      const unsigned mb = (kt < 8) ? mbits0 : mbits1;
      e = ((mb >> ((kt & 7) * 4 + r)) & 1u) ? e : 0.f;
      sreg[kt][r] = e;                 // reuse in pass 2: p = e * Cr
      l += e;
    }
#pragma unroll
    for (int off = 1; off < 16; off <<= 1) l += __shfl_xor(l, off, 64);
    if (col == 0) {
      partM[wave * 16 + quad * 4 + r] = m;
      partL[wave * 16 + quad * 4 + r] = l;
    }
  }
  __syncthreads();
  if (tid < TQ) {
    float M = -INFINITY, L = 0.f;
#pragma unroll
    for (int w = 0; w < 4; ++w) {
      float m_ = partM[w * 16 + tid], l_ = partL[w * 16 + tid];
      float mn = fmaxf(M, m_);
      L = L * __expf(M - mn) + l_ * __expf(m_ - mn);  // finite inputs
      M = mn;
    }
    rowM[tid] = M;
    rowS[tid] = (QM[b * SLQ + q0 + tid] && L > 0.f) ? (1.f / L) : 0.f;
  }
  __syncthreads();
#pragma unroll
  for (int r = 0; r < 4; ++r)
    Cr[r] = __expf(Mw[r] - rowM[quad * 4 + r]) * rowS[quad * 4 + r];

  // ====== Pass 2 (barrier-free): 8 steps of 2 tiles, V via private LDS =====
  f32x4 acco[4] = {{0.f,0.f,0.f,0.f},{0.f,0.f,0.f,0.f},
                   {0.f,0.f,0.f,0.f},{0.f,0.f,0.f,0.f}};
#pragma unroll
  for (int st = 0; st < 8; ++st) {
    const int kt0 = st * 2, kt1 = kt0 + 1;
    // stage V rows (32: tile kt0 then kt1) into private slice
#pragma unroll
    for (int j = 0; j < 8; ++j)
      *(u16x4*)&Vw[(j * 4 + lrow) * VSTR + lc4] = cvt4(vreg[j]);

    // p = e*Cr: write back into sreg (f32, for staged output) + bf16 slice
#pragma unroll
    for (int r = 0; r < 4; ++r) {
      float p0 = sreg[kt0][r] * Cr[r];
      float p1 = sreg[kt1][r] * Cr[r];
      sreg[kt0][r] = p0;
      sreg[kt1][r] = p1;
      Pw[(quad * 4 + r) * PSTR + col]      = f2bf(p0);
      Pw[(quad * 4 + r) * PSTR + 16 + col] = f2bf(p1);
    }

    // prefetch next step's V
    if (st < 7) {
#pragma unroll
      for (int j = 0; j < 8; ++j)
        vreg[j] = vb4[(size_t)((st * 2 + 2 + (j >> 2)) * TK + wave * 16 + (j & 3) * 4 + lrow) * 16
                      + col];
    }

    // A = P[q=col][kk=quad*8+j]; B = V[kk=quad*8+j][d=n0*16+col]
    bf16x8 ap = __builtin_bit_cast(bf16x8, *(const u16x8*)&Pw[col * PSTR + quad * 8]);
#pragma unroll
    for (int n0 = 0; n0 < 4; ++n0) {
      u16x8 rv;
#pragma unroll
      for (int j = 0; j < 8; ++j)
        rv[j] = Vw[(quad * 8 + j) * VSTR + n0 * 16 + col];
      acco[n0] = __builtin_amdgcn_mfma_f32_16x16x32_bf16(
          ap, __builtin_bit_cast(bf16x8, rv), acco[n0], 0, 0, 0);
    }
  }

  // ====== final O: per-wave partial -> LDS -> cross-wave reduce ============
  // HARD FENCE: Ow (f32) aliases Vw/Pw-read bytes (u16). TBAA lets the
  // scheduler move the f32 stores above the u16 reads without this barrier
  // (compiler memory fence + wave sync) -- the R10 nondeterminism.
  __syncthreads();
#pragma unroll
  for (int n0 = 0; n0 < 4; ++n0)
#pragma unroll
    for (int r = 0; r < 4; ++r)
      Ow[(quad * 4 + r) * OSTR + n0 * 16 + col] = acco[n0][r];
  __syncthreads();
  {
    const int qq = tid >> 4, dd = (tid & 15) * 4;
    f32x4 s = {0.f, 0.f, 0.f, 0.f};
#pragma unroll
    for (int w = 0; w < 4; ++w) {
      const float* Os = (const float*)(RAW + w * (32 * VSTR * 2));
      s += *(const f32x4*)&Os[qq * OSTR + dd];
    }
    *(f32x4*)&OUT_AV[((size_t)b * SLQ + q0 + qq) * DH + dd] = s;
  }
  __syncthreads();   // region A now free for P staging

  // ====== P f32 output: stage 4-row chunks, drain contiguous rows ==========
#pragma unroll
  for (int c = 0; c < 4; ++c) {
    if (quad == c) {
#pragma unroll
      for (int kt = 0; kt < NKT; ++kt)
#pragma unroll
        for (int r = 0; r < 4; ++r)
          Pst[r * PGSTR + kt * TK + wave * 16 + col] = sreg[kt][r];
    }
    __syncthreads();
    {
      float* dst = OUT_P + mbase + (size_t)(c * 4) * SLK;
#pragma unroll
      for (int i = 0; i < 4; ++i)
        *(f32x4*)&dst[(size_t)i * SLK + tid * 4] =
            *(const f32x4*)&Pst[i * PGSTR + tid * 4];
    }
    if (c < 3) __syncthreads();
  }
}

extern "C" void kernel_launch(void* const* d_in, const int* in_sizes, int n_in,
                              void* d_out, int out_size, void* d_ws, size_t ws_size,
                              hipStream_t stream) {
  const float* q  = (const float*)d_in[0];
  const float* k  = (const float*)d_in[1];
  const float* v  = (const float*)d_in[2];
  const int*   qm = (const int*)d_in[3];
  const int*   km = (const int*)d_in[4];
  const int*   mk = (const int*)d_in[5];
  float* out_av = (float*)d_out;                          // [B,LQ,D]
  float* out_p  = out_av + (size_t)NB * SLQ * DH;         // [B,LQ,LK]
  sdpa_fused<<<dim3(NB * (SLQ / TQ)), dim3(256), 0, stream>>>(q, k, v, qm, km, mk, out_av, out_p);
}